// Round 19
// baseline (107.955 us; speedup 1.0000x reference)
//
#include <hip/hip_runtime.h>
#include <hip/hip_bf16.h>
#include <cstddef>

#define T_DIM 2048
#define D_DIM 1024
#define GAMMA_F 0.96875f

typedef __attribute__((ext_vector_type(8))) short bf16x8;
typedef __attribute__((ext_vector_type(4))) ushort ushortx4;
typedef __attribute__((ext_vector_type(4))) float f32x4;

#define AS1 __attribute__((address_space(1)))
#define AS3 __attribute__((address_space(3)))

static __device__ inline ushort f2bs(float f) {
    __hip_bfloat16 h = __float2bfloat16(f);
    return *reinterpret_cast<ushort*>(&h);
}

// compile-time gamma^n
constexpr float gpw(int n) {
    float r = 1.f;
    for (int i = 0; i < n; ++i) r *= GAMMA_F;
    return r;
}

// Exhaustive + fail-closed: an unmatched N is a COMPILE ERROR, never a no-op.
template <int N>
static __device__ __forceinline__ void vm_wait() {
    static_assert(N == 0 || N == 2 || N == 3 || N == 4 || N == 6 || N == 8,
                  "vm_wait<N>: N not in emitted set");
    if constexpr (N == 0)      asm volatile("s_waitcnt vmcnt(0)" ::: "memory");
    else if constexpr (N == 2) asm volatile("s_waitcnt vmcnt(2)" ::: "memory");
    else if constexpr (N == 3) asm volatile("s_waitcnt vmcnt(3)" ::: "memory");
    else if constexpr (N == 4) asm volatile("s_waitcnt vmcnt(4)" ::: "memory");
    else if constexpr (N == 6) asm volatile("s_waitcnt vmcnt(6)" ::: "memory");
    else if constexpr (N == 8) asm volatile("s_waitcnt vmcnt(8)" ::: "memory");
}
static __device__ __forceinline__ void raw_barrier() {
    asm volatile("s_barrier" ::: "memory");
}
static __device__ __forceinline__ void lgkm0() {
    asm volatile("s_waitcnt lgkmcnt(0)" ::: "memory");
}

// Device-scope semaphore (round-15-validated protocol; co-residency by
// capacity arithmetic: 512 blocks x 512 thr, <=128 VGPR, 64 KB LDS ->
// exactly 2 blocks/CU x 256 CU = all resident -> no deadlock).
static __device__ __forceinline__ void sem_signal(unsigned* sem) {
    __syncthreads();                 // all stores of the block drained
    if (threadIdx.x == 0) {
        __threadfence();             // agent-scope: publish to device
        atomicAdd(sem, 1u);          // device-scope by default (m20)
    }
}
static __device__ __forceinline__ void sem_wait(unsigned* sem, unsigned target) {
    if (threadIdx.x == 0) {
        while (__hip_atomic_load(sem, __ATOMIC_RELAXED, __HIP_MEMORY_SCOPE_AGENT) < target)
            __builtin_amdgcn_s_sleep(16);
        __threadfence();             // agent-scope acquire
    }
    __syncthreads();
}

// ---------------------------------------------------------------------------
// K_prep: z=0: Wk -> WTk [N][K] bf16; z=1: Wq -> WTq; z=2: wv_sum[i]=sum Wv[i][:]
// ---------------------------------------------------------------------------
__global__ __launch_bounds__(256) void k_prep(const float* __restrict__ Wk,
                                              const float* __restrict__ Wq,
                                              const float* __restrict__ Wv,
                                              ushort* __restrict__ WTk,
                                              ushort* __restrict__ WTq,
                                              float* __restrict__ wv_sum) {
    const int tid = threadIdx.x;
    if (blockIdx.z == 2) {
        __shared__ float red[4];
        const int i = blockIdx.y * 32 + blockIdx.x;
        const float* row = Wv + (size_t)i * D_DIM;
        float p = 0.f;
        for (int c = tid; c < D_DIM; c += 256) p += row[c];
        for (int o = 32; o; o >>= 1) p += __shfl_down(p, o);
        if ((tid & 63) == 0) red[tid >> 6] = p;
        __syncthreads();
        if (tid == 0) wv_sum[i] = red[0] + red[1] + red[2] + red[3];
        return;
    }
    const float* W = (blockIdx.z == 0) ? Wk : Wq;
    ushort* WT     = (blockIdx.z == 0) ? WTk : WTq;
    __shared__ float tile[32][33];          // [k][n]
    const int tx = tid & 31, ty = tid >> 5; // 32 x 8
    const int kb = blockIdx.x * 32, nb = blockIdx.y * 32;
    #pragma unroll
    for (int r = 0; r < 4; ++r)
        tile[ty + 8 * r][tx] = W[(size_t)(kb + ty + 8 * r) * 1024 + nb + tx];
    __syncthreads();
    #pragma unroll
    for (int r = 0; r < 4; ++r)
        WT[(size_t)(nb + ty + 8 * r) * 1024 + kb + tx] =
            f2bs(tile[tx][ty + 8 * r]);
}

// ---------------------------------------------------------------------------
// K1 (register-resident): per t: vsum[b] = x[b,t,:].wv_sum;
// y[t,i] = sum_b x[b,t,i]*vsum[b]. Emits bf16 yb [T,D], xb [B*T,D].
// ---------------------------------------------------------------------------
__global__ __launch_bounds__(256) void k_vsum_y(const float* __restrict__ x,
                                                const float* __restrict__ wv_sum,
                                                ushort* __restrict__ yb,
                                                ushort* __restrict__ xb) {
    __shared__ float red[4][4];   // [wave][b]
    const int t = blockIdx.x;
    const int tid = threadIdx.x;
    const int lane = tid & 63, wv = tid >> 6;
    const int i0 = tid * 4;

    const float4 wvs = *(const float4*)(wv_sum + i0);

    float4 xv[4];
    #pragma unroll
    for (int b = 0; b < 4; ++b)
        xv[b] = *(const float4*)(x + ((size_t)b * T_DIM + t) * D_DIM + i0);

    #pragma unroll
    for (int b = 0; b < 4; ++b) {
        float p = xv[b].x * wvs.x + xv[b].y * wvs.y +
                  xv[b].z * wvs.z + xv[b].w * wvs.w;
        for (int o = 32; o; o >>= 1) p += __shfl_down(p, o);
        if (lane == 0) red[wv][b] = p;
    }
    __syncthreads();

    float vs[4];
    #pragma unroll
    for (int b = 0; b < 4; ++b)
        vs[b] = red[0][b] + red[1][b] + red[2][b] + red[3][b];

    #pragma unroll
    for (int b = 0; b < 4; ++b) {
        ushortx4 xw;
        xw[0] = f2bs(xv[b].x); xw[1] = f2bs(xv[b].y);
        xw[2] = f2bs(xv[b].z); xw[3] = f2bs(xv[b].w);
        *(ushortx4*)(xb + ((size_t)b * T_DIM + t) * D_DIM + i0) = xw;
    }

    ushortx4 yw;
    {
        float a0 = 0.f, a1 = 0.f, a2 = 0.f, a3 = 0.f;
        #pragma unroll
        for (int b = 0; b < 4; ++b) {
            a0 += xv[b].x * vs[b];
            a1 += xv[b].y * vs[b];
            a2 += xv[b].z * vs[b];
            a3 += xv[b].w * vs[b];
        }
        yw[0] = f2bs(a0); yw[1] = f2bs(a1); yw[2] = f2bs(a2); yw[3] = f2bs(a3);
    }
    *(ushortx4*)(yb + (size_t)t * D_DIM + i0) = yw;
}

// ---------------------------------------------------------------------------
// scan2 body (512 thr, round-15-validated): carries + scrambled write
// S2[(t&1)*1024+col][t>>1] = S[t][col]. First 256 threads compute, all write.
// Uses the caller's LDS arena (needs 33.3 KB).
// ---------------------------------------------------------------------------
#define SC_L 32

static __device__ __forceinline__ void scan2_body(char* smem, int bx, int by,
                                                  const float* __restrict__ m,
                                                  const float* __restrict__ tot,
                                                  float* __restrict__ S2) {
    float (*ls)[65] = (float(*)[65])smem;   // [128][65] = 33 KB
    const int tid = threadIdx.x;
    if (tid < 256) {
        const int cl = tid & 63;
        const int ch = tid >> 6;              // 0..3
        const int col = bx * 64 + cl;
        const int chg = by * 4 + ch;
        const int t0 = chg * SC_L;

        constexpr float gL = gpw(SC_L);
        float carry = 0.f, f = 1.f;
        for (int j = chg - 1; j >= 0; --j) {
            carry += f * tot[(size_t)j * D_DIM + col];
            f *= gL;
        }

        float r = carry, s1 = 0.f;
        #pragma unroll 4
        for (int k = 0; k < SC_L; ++k) {
            const int t = t0 + k;
            const float a = (t == 0) ? 0.f : m[(size_t)t * D_DIM + col];
            r = GAMMA_F * r + a;
            ls[ch * SC_L + k][cl] = r;
            if (t == 1) s1 = r;
        }
        if (by == 0 && ch == 0) ls[0][cl] = s1;   // S[0] = S[1]
    }
    __syncthreads();

    const int c0 = bx * 64;
    const int tB = by * 128;
    for (int e = tid; e < 128 * 64; e += 512) {
        const int rr = e >> 6;            // 0..127
        const int j  = e & 63;
        const int hi = rr >> 6, cl2 = rr & 63;
        S2[(size_t)((hi << 10) + c0 + cl2) * D_DIM + (tB >> 1) + j] =
            ls[2 * j + hi][cl2];
    }
    __syncthreads();   // LDS handoff before the GEMM stage overwrites arena
}

// ---------------------------------------------------------------------------
// K3: bf16 MFMA GEMM, 512 threads = 8 waves (4x2), wave-tile (MF*16)x(NF*16);
// block tile BM=64*MF x BN=32*NF. BK=64. Dbuf + COUNTED vmcnt; XOR swizzle
// both sides (rule #21).
// MODE 0 (m-GEMM): write C + FUSED scan1 chunk totals -> tot.
// MODE 1 (Q-GEMM + FUSED scan2): blocks lin<256 run scan2_body (in the LDS
//   arena, BEFORE stage(0,0)) then sem_signal; ALL blocks run the K-loop
//   (doesn't need S2); sem_wait(256) only before the epilogue, where
//   out[r,d] = acc * S2[r & 2047][d]. scan2 hides under the K-loop.
// ---------------------------------------------------------------------------
template <int MF, int NF, int MODE>
__global__ __launch_bounds__(512, 4) void k_gemm(const ushort* __restrict__ A,
                                                 const ushort* __restrict__ BT,
                                                 float* __restrict__ C,
                                                 float* __restrict__ S2,
                                                 float* __restrict__ tot,
                                                 const float* __restrict__ m_in,
                                                 unsigned* sem) {
    static_assert(MODE != 0 || MF == 2, "fused scan1 requires 32-row wave tiles");
    constexpr int BM = 4 * MF * 16;
    constexpr int BN = 2 * NF * 16;
    constexpr int LOADS = BM / 64 + BN / 64;   // gload_lds per thread per stage
    __shared__ ushort As[2][BM][64];
    __shared__ ushort Bs[2][BN][64];
    const int tid = threadIdx.x;
    const int lane = tid & 63, wid = tid >> 6;   // 8 waves
    const int wr = wid >> 1, wc = wid & 1;       // 4 x 2
    const int rowBase = blockIdx.x * BM;
    const int colBase = blockIdx.y * BN;

    // ---- MODE 1: fused scan2 on the first 256 blocks (before LDS staging)
    if (MODE == 1) {
        const int lin = blockIdx.y * gridDim.x + blockIdx.x;
        if (lin < 256) {
            static_assert(MODE != 1 || sizeof(As) + sizeof(Bs) >= 128 * 65 * 4,
                          "scan2 arena");
            scan2_body((char*)&As[0][0][0], lin & 15, lin >> 4, m_in, tot, S2);
            sem_signal(sem);
        }
    }

    f32x4 acc[MF][NF];
    #pragma unroll
    for (int i = 0; i < MF; ++i)
        #pragma unroll
        for (int j = 0; j < NF; ++j) acc[i][j] = f32x4{0.f, 0.f, 0.f, 0.f};

    auto stage = [&](int buf, int kb) {
        #pragma unroll
        for (int q = 0; q < BM / 64; ++q) {
            const int s = q * 8192 + tid * 16;           // linear LDS byte
            const int r = s >> 7, grp = (s >> 4) & 7;
            const int gcol = kb + (((grp ^ (r & 7)) & 7) << 3);
            __builtin_amdgcn_global_load_lds(
                (const AS1 void*)(A + (size_t)(rowBase + r) * 1024 + gcol),
                (AS3 void*)((AS3 char*)&As[buf][0][0] + s), 16, 0, 0);
        }
        #pragma unroll
        for (int q = 0; q < BN / 64; ++q) {
            const int s = q * 8192 + tid * 16;
            const int r = s >> 7, grp = (s >> 4) & 7;
            const int gcol = kb + (((grp ^ (r & 7)) & 7) << 3);
            __builtin_amdgcn_global_load_lds(
                (const AS1 void*)(BT + (size_t)(colBase + r) * 1024 + gcol),
                (AS3 void*)((AS3 char*)&Bs[buf][0][0] + s), 16, 0, 0);
        }
    };

    stage(0, 0);                           // waited inside iter 0

    #pragma unroll 2
    for (int kt = 0; kt < 16; ++kt) {
        const int cur = kt & 1;
        if (kt < 15) {
            stage(cur ^ 1, (kt + 1) * 64); // next tile's loads join the queue
            vm_wait<LOADS>();              // wait ONLY for tile kt's loads
        } else {
            vm_wait<0>();
        }
        raw_barrier();                     // buf[cur] valid for all waves

        bf16x8 af[2][MF], bfv[2][NF];
        #pragma unroll
        for (int ks = 0; ks < 2; ++ks) {
            const int kg = ks * 4 + (lane >> 4);
            #pragma unroll
            for (int mi = 0; mi < MF; ++mi) {
                const int r = wr * (MF * 16) + mi * 16 + (lane & 15);
                af[ks][mi] = *(const bf16x8*)((const char*)&As[cur][0][0] +
                                              r * 128 + (((kg ^ (r & 7)) & 7) << 4));
            }
            #pragma unroll
            for (int ni = 0; ni < NF; ++ni) {
                const int r = wc * (NF * 16) + ni * 16 + (lane & 15);
                bfv[ks][ni] = *(const bf16x8*)((const char*)&Bs[cur][0][0] +
                                               r * 128 + (((kg ^ (r & 7)) & 7) << 4));
            }
        }
        #pragma unroll
        for (int ks = 0; ks < 2; ++ks)
            #pragma unroll
            for (int mi = 0; mi < MF; ++mi)
                #pragma unroll
                for (int ni = 0; ni < NF; ++ni)
                    acc[mi][ni] = __builtin_amdgcn_mfma_f32_16x16x32_bf16(
                        af[ks][mi], bfv[ks][ni], acc[mi][ni], 0, 0, 0);

        lgkm0();
        raw_barrier();                     // reads done; next stage may overwrite
    }

    // ---- MODE 1: make sure ALL scan2 writers have published S2
    if (MODE == 1) sem_wait(sem, 256);

    #pragma unroll
    for (int mi = 0; mi < MF; ++mi) {
        #pragma unroll
        for (int ni = 0; ni < NF; ++ni) {
            const int col = colBase + wc * (NF * 16) + ni * 16 + (lane & 15);
            #pragma unroll
            for (int q = 0; q < 4; ++q) {
                const int row = rowBase + wr * (MF * 16) + mi * 16 + (lane >> 4) * 4 + q;
                float v = acc[mi][ni][q];
                if (MODE == 1)
                    v *= S2[(size_t)(row & (T_DIM - 1)) * D_DIM + col];
                C[(size_t)row * D_DIM + col] = v;
            }
        }
    }

    if (MODE == 0) {
        // Fused scan1: wave covers scan chunk (bx*4 + wr); weight g^(31-local_r)
        const int h = lane >> 4;
        const int t3 = 3 - h;
        const float A0 = ((t3 & 1) ? gpw(4) : 1.f) * ((t3 & 2) ? gpw(8) : 1.f);
        const int chunk = blockIdx.x * 4 + wr;
        #pragma unroll
        for (int ni = 0; ni < NF; ++ni) {
            float part = 0.f;
            #pragma unroll
            for (int mi = 0; mi < MF; ++mi)
                #pragma unroll
                for (int q = 0; q < 4; ++q)
                    part += (A0 * gpw(16 * (MF - 1 - mi) + (3 - q))) * acc[mi][ni][q];
            if (chunk == 0 && h == 0)      // exclude t = 0
                part -= (A0 * gpw(16 * (MF - 1) + 3)) * acc[0][ni][0];
            part += __shfl_xor(part, 16);
            part += __shfl_xor(part, 32);
            if (h == 0) {
                const int col = colBase + wc * (NF * 16) + ni * 16 + (lane & 15);
                tot[(size_t)chunk * D_DIM + col] = part;
            }
        }
    }
}

// ---------------------------------------------------------------------------
extern "C" void kernel_launch(void* const* d_in, const int* in_sizes, int n_in,
                              void* d_out, int out_size, void* d_ws, size_t ws_size,
                              hipStream_t stream) {
    const float* x  = (const float*)d_in[0];   // [4,2048,1024]
    const float* Wq = (const float*)d_in[1];
    const float* Wk = (const float*)d_in[2];
    const float* Wv = (const float*)d_in[3];
    float* out = (float*)d_out;                // [4,2048,1024] fp32
    char* ws = (char*)d_ws;

    // ws layout (41.3 MB):
    ushort* xb  = (ushort*)(ws);                    // 16 MB  [B*T,D] bf16
    float*  m   = (float*)(ws + (16u << 20));       //  8 MB  [T,D] fp32
    ushort* yb  = (ushort*)(ws + (24u << 20));      //  4 MB  [T,D] bf16
    ushort* WTk = (ushort*)(ws + (28u << 20));      //  2 MB
    ushort* WTq = (ushort*)(ws + (30u << 20));      //  2 MB
    float*  S2  = (float*)(ws + (32u << 20));       //  8 MB  scrambled S fp32
    float*  tot = (float*)(ws + (40u << 20));       //  256 KB (dedicated)
    unsigned* sem = (unsigned*)(ws + (40u << 20) + (512u << 10)); // 256 B
    float*  wv_sum = m;                 // m row 0: never read later (t=0 -> 0)

    // semaphore reset (stream-ordered, graph-capturable)
    hipMemsetAsync(sem, 0, 256, stream);

    dim3 gP(32, 32, 3);
    k_prep<<<gP, 256, 0, stream>>>(Wk, Wq, Wv, WTk, WTq, wv_sum);

    k_vsum_y<<<T_DIM, 256, 0, stream>>>(x, wv_sum, (ushort*)yb, (ushort*)xb);

    // m = y @ Wk (+ fused scan1 -> tot): tile 128x64, grid (16,16), 8 waves
    dim3 gm(T_DIM / 128, D_DIM / 64);
    k_gemm<2, 2, 0><<<gm, 512, 0, stream>>>(yb, WTk, m, nullptr, tot,
                                            nullptr, nullptr);

    // out = S2 ⊙ (x @ Wq), scan2 fused into blocks 0..255 (hides under K-loop)
    dim3 gq((4 * T_DIM) / 128, D_DIM / 128);
    k_gemm<2, 4, 1><<<gq, 512, 0, stream>>>(xb, WTq, out, S2, tot, m, sem);
}

// Round 20
// 72.532 us; speedup vs baseline: 1.4884x; 1.4884x over previous
//
#include <hip/hip_runtime.h>
#include <hip/hip_bf16.h>
#include <cstddef>

#define T_DIM 2048
#define D_DIM 1024
#define GAMMA_F 0.96875f

typedef __attribute__((ext_vector_type(8))) short bf16x8;
typedef __attribute__((ext_vector_type(4))) ushort ushortx4;
typedef __attribute__((ext_vector_type(8))) ushort ushortx8;
typedef __attribute__((ext_vector_type(4))) float f32x4;

#define AS1 __attribute__((address_space(1)))
#define AS3 __attribute__((address_space(3)))

static __device__ inline ushort f2bs(float f) {
    __hip_bfloat16 h = __float2bfloat16(f);
    return *reinterpret_cast<ushort*>(&h);
}

// compile-time gamma^n
constexpr float gpw(int n) {
    float r = 1.f;
    for (int i = 0; i < n; ++i) r *= GAMMA_F;
    return r;
}

// Exhaustive + fail-closed: an unmatched N is a COMPILE ERROR, never a no-op.
template <int N>
static __device__ __forceinline__ void vm_wait() {
    static_assert(N == 0 || N == 2 || N == 3 || N == 4 || N == 6 || N == 8,
                  "vm_wait<N>: N not in emitted set");
    if constexpr (N == 0)      asm volatile("s_waitcnt vmcnt(0)" ::: "memory");
    else if constexpr (N == 2) asm volatile("s_waitcnt vmcnt(2)" ::: "memory");
    else if constexpr (N == 3) asm volatile("s_waitcnt vmcnt(3)" ::: "memory");
    else if constexpr (N == 4) asm volatile("s_waitcnt vmcnt(4)" ::: "memory");
    else if constexpr (N == 6) asm volatile("s_waitcnt vmcnt(6)" ::: "memory");
    else if constexpr (N == 8) asm volatile("s_waitcnt vmcnt(8)" ::: "memory");
}
static __device__ __forceinline__ void raw_barrier() {
    asm volatile("s_barrier" ::: "memory");
}
static __device__ __forceinline__ void lgkm0() {
    asm volatile("s_waitcnt lgkmcnt(0)" ::: "memory");
}

// ---------------------------------------------------------------------------
// K_prep: z=0: Wk -> WTk [N][K] bf16; z=1: Wq -> WTq; z=2: wv_sum[i]=sum Wv[i][:]
// ---------------------------------------------------------------------------
__global__ __launch_bounds__(256) void k_prep(const float* __restrict__ Wk,
                                              const float* __restrict__ Wq,
                                              const float* __restrict__ Wv,
                                              ushort* __restrict__ WTk,
                                              ushort* __restrict__ WTq,
                                              float* __restrict__ wv_sum) {
    const int tid = threadIdx.x;
    if (blockIdx.z == 2) {
        __shared__ float red[4];
        const int i = blockIdx.y * 32 + blockIdx.x;
        const float* row = Wv + (size_t)i * D_DIM;
        float p = 0.f;
        for (int c = tid; c < D_DIM; c += 256) p += row[c];
        for (int o = 32; o; o >>= 1) p += __shfl_down(p, o);
        if ((tid & 63) == 0) red[tid >> 6] = p;
        __syncthreads();
        if (tid == 0) wv_sum[i] = red[0] + red[1] + red[2] + red[3];
        return;
    }
    const float* W = (blockIdx.z == 0) ? Wk : Wq;
    ushort* WT     = (blockIdx.z == 0) ? WTk : WTq;
    __shared__ float tile[32][33];          // [k][n]
    const int tx = tid & 31, ty = tid >> 5; // 32 x 8
    const int kb = blockIdx.x * 32, nb = blockIdx.y * 32;
    #pragma unroll
    for (int r = 0; r < 4; ++r)
        tile[ty + 8 * r][tx] = W[(size_t)(kb + ty + 8 * r) * 1024 + nb + tx];
    __syncthreads();
    #pragma unroll
    for (int r = 0; r < 4; ++r)
        WT[(size_t)(nb + ty + 8 * r) * 1024 + kb + tx] =
            f2bs(tile[tx][ty + 8 * r]);
}

// ---------------------------------------------------------------------------
// K1 (register-resident): per t: vsum[b] = x[b,t,:].wv_sum;
// y[t,i] = sum_b x[b,t,i]*vsum[b]. Each thread holds float4 of all 4 batch
// rows in registers (no LDS row staging); LDS only for the 4x4 partial
// reduce. Emits bf16 yb [T,D] and xb [B*T,D] straight from registers.
// ---------------------------------------------------------------------------
__global__ __launch_bounds__(256) void k_vsum_y(const float* __restrict__ x,
                                                const float* __restrict__ wv_sum,
                                                ushort* __restrict__ yb,
                                                ushort* __restrict__ xb) {
    __shared__ float red[4][4];   // [wave][b]
    const int t = blockIdx.x;
    const int tid = threadIdx.x;
    const int lane = tid & 63, wv = tid >> 6;
    const int i0 = tid * 4;

    const float4 wvs = *(const float4*)(wv_sum + i0);

    float4 xv[4];
    #pragma unroll
    for (int b = 0; b < 4; ++b)
        xv[b] = *(const float4*)(x + ((size_t)b * T_DIM + t) * D_DIM + i0);

    #pragma unroll
    for (int b = 0; b < 4; ++b) {
        float p = xv[b].x * wvs.x + xv[b].y * wvs.y +
                  xv[b].z * wvs.z + xv[b].w * wvs.w;
        for (int o = 32; o; o >>= 1) p += __shfl_down(p, o);
        if (lane == 0) red[wv][b] = p;
    }
    __syncthreads();

    float vs[4];
    #pragma unroll
    for (int b = 0; b < 4; ++b)
        vs[b] = red[0][b] + red[1][b] + red[2][b] + red[3][b];

    // xb writes (bf16, 8B per store)
    #pragma unroll
    for (int b = 0; b < 4; ++b) {
        ushortx4 xw;
        xw[0] = f2bs(xv[b].x); xw[1] = f2bs(xv[b].y);
        xw[2] = f2bs(xv[b].z); xw[3] = f2bs(xv[b].w);
        *(ushortx4*)(xb + ((size_t)b * T_DIM + t) * D_DIM + i0) = xw;
    }

    // y row
    ushortx4 yw;
    {
        float a0 = 0.f, a1 = 0.f, a2 = 0.f, a3 = 0.f;
        #pragma unroll
        for (int b = 0; b < 4; ++b) {
            a0 += xv[b].x * vs[b];
            a1 += xv[b].y * vs[b];
            a2 += xv[b].z * vs[b];
            a3 += xv[b].w * vs[b];
        }
        yw[0] = f2bs(a0); yw[1] = f2bs(a1); yw[2] = f2bs(a2); yw[3] = f2bs(a3);
    }
    *(ushortx4*)(yb + (size_t)t * D_DIM + i0) = yw;
}

// ---------------------------------------------------------------------------
// K3: bf16 MFMA GEMM, 512 threads = 8 waves (4 m-rows x 2 n-cols),
// wave-tile (MF*16) x (NF*16); block tile BM=64*MF x BN=32*NF. BK=64.
// Double-buffered LDS + COUNTED vmcnt; XOR swizzle both sides (rule #21).
// MODE 0 (m-GEMM): write C and FUSED scan1 (in-register gamma-weighted
//   chunk totals, shfl_xor 16/32, t=0 term excluded).
// MODE 1 (Q-GEMM): out[r,d] = acc * S2[r & 2047][d] (pre-scrambled fp32).
// ---------------------------------------------------------------------------
template <int MF, int NF, int MODE>
__global__ __launch_bounds__(512, 4) void k_gemm(const ushort* __restrict__ A,
                                                 const ushort* __restrict__ BT,
                                                 float* __restrict__ C,
                                                 const float* __restrict__ S2,
                                                 float* __restrict__ tot) {
    static_assert(MODE != 0 || MF == 2, "fused scan1 requires 32-row wave tiles");
    constexpr int BM = 4 * MF * 16;
    constexpr int BN = 2 * NF * 16;
    constexpr int LOADS = BM / 64 + BN / 64;   // gload_lds per thread per stage
    __shared__ ushort As[2][BM][64];
    __shared__ ushort Bs[2][BN][64];
    const int tid = threadIdx.x;
    const int lane = tid & 63, wid = tid >> 6;   // 8 waves
    const int wr = wid >> 1, wc = wid & 1;       // 4 x 2
    const int rowBase = blockIdx.x * BM;
    const int colBase = blockIdx.y * BN;

    f32x4 acc[MF][NF];
    #pragma unroll
    for (int i = 0; i < MF; ++i)
        #pragma unroll
        for (int j = 0; j < NF; ++j) acc[i][j] = f32x4{0.f, 0.f, 0.f, 0.f};

    auto stage = [&](int buf, int kb) {
        #pragma unroll
        for (int q = 0; q < BM / 64; ++q) {
            const int s = q * 8192 + tid * 16;           // linear LDS byte
            const int r = s >> 7, grp = (s >> 4) & 7;
            const int gcol = kb + (((grp ^ (r & 7)) & 7) << 3);
            __builtin_amdgcn_global_load_lds(
                (const AS1 void*)(A + (size_t)(rowBase + r) * 1024 + gcol),
                (AS3 void*)((AS3 char*)&As[buf][0][0] + s), 16, 0, 0);
        }
        #pragma unroll
        for (int q = 0; q < BN / 64; ++q) {
            const int s = q * 8192 + tid * 16;
            const int r = s >> 7, grp = (s >> 4) & 7;
            const int gcol = kb + (((grp ^ (r & 7)) & 7) << 3);
            __builtin_amdgcn_global_load_lds(
                (const AS1 void*)(BT + (size_t)(colBase + r) * 1024 + gcol),
                (AS3 void*)((AS3 char*)&Bs[buf][0][0] + s), 16, 0, 0);
        }
    };

    stage(0, 0);                           // waited inside iter 0

    #pragma unroll 2
    for (int kt = 0; kt < 16; ++kt) {
        const int cur = kt & 1;
        if (kt < 15) {
            stage(cur ^ 1, (kt + 1) * 64); // next tile's loads join the queue
            vm_wait<LOADS>();              // wait ONLY for tile kt's loads
        } else {
            vm_wait<0>();
        }
        raw_barrier();                     // buf[cur] valid for all waves

        bf16x8 af[2][MF], bfv[2][NF];
        #pragma unroll
        for (int ks = 0; ks < 2; ++ks) {
            const int kg = ks * 4 + (lane >> 4);
            #pragma unroll
            for (int mi = 0; mi < MF; ++mi) {
                const int r = wr * (MF * 16) + mi * 16 + (lane & 15);
                af[ks][mi] = *(const bf16x8*)((const char*)&As[cur][0][0] +
                                              r * 128 + (((kg ^ (r & 7)) & 7) << 4));
            }
            #pragma unroll
            for (int ni = 0; ni < NF; ++ni) {
                const int r = wc * (NF * 16) + ni * 16 + (lane & 15);
                bfv[ks][ni] = *(const bf16x8*)((const char*)&Bs[cur][0][0] +
                                               r * 128 + (((kg ^ (r & 7)) & 7) << 4));
            }
        }
        #pragma unroll
        for (int ks = 0; ks < 2; ++ks)
            #pragma unroll
            for (int mi = 0; mi < MF; ++mi)
                #pragma unroll
                for (int ni = 0; ni < NF; ++ni)
                    acc[mi][ni] = __builtin_amdgcn_mfma_f32_16x16x32_bf16(
                        af[ks][mi], bfv[ks][ni], acc[mi][ni], 0, 0, 0);

        lgkm0();
        raw_barrier();                     // reads done; next stage may overwrite
    }

    #pragma unroll
    for (int mi = 0; mi < MF; ++mi) {
        #pragma unroll
        for (int ni = 0; ni < NF; ++ni) {
            const int col = colBase + wc * (NF * 16) + ni * 16 + (lane & 15);
            #pragma unroll
            for (int q = 0; q < 4; ++q) {
                const int row = rowBase + wr * (MF * 16) + mi * 16 + (lane >> 4) * 4 + q;
                float v = acc[mi][ni][q];
                if (MODE == 1)
                    v *= S2[(size_t)(row & (T_DIM - 1)) * D_DIM + col];
                C[(size_t)row * D_DIM + col] = v;
            }
        }
    }

    if (MODE == 0) {
        // Fused scan1: wave covers scan chunk (bx*4 + wr); weight g^(31-local_r)
        const int h = lane >> 4;
        const int t3 = 3 - h;
        const float A0 = ((t3 & 1) ? gpw(4) : 1.f) * ((t3 & 2) ? gpw(8) : 1.f);
        const int chunk = blockIdx.x * 4 + wr;
        #pragma unroll
        for (int ni = 0; ni < NF; ++ni) {
            float part = 0.f;
            #pragma unroll
            for (int mi = 0; mi < MF; ++mi)
                #pragma unroll
                for (int q = 0; q < 4; ++q)
                    part += (A0 * gpw(16 * (MF - 1 - mi) + (3 - q))) * acc[mi][ni][q];
            if (chunk == 0 && h == 0)      // exclude t = 0
                part -= (A0 * gpw(16 * (MF - 1) + 3)) * acc[0][ni][0];
            part += __shfl_xor(part, 16);
            part += __shfl_xor(part, 32);
            if (h == 0) {
                const int col = colBase + wc * (NF * 16) + ni * 16 + (lane & 15);
                tot[(size_t)chunk * D_DIM + col] = part;
            }
        }
    }
}

// ---------------------------------------------------------------------------
// K_scan2: apply cross-chunk carries and write SCRAMBLED fp32
// S2[(t&1)*1024 + col][t>>1] = S[t][col], via LDS transpose tile.
// carry = sum_{j<chg} (g^32)^(chg-1-j) * tot[j].
// ---------------------------------------------------------------------------
#define SC_L 32
#define SC_NC 64

__global__ __launch_bounds__(256) void k_scan2(const float* __restrict__ m,
                                               const float* __restrict__ tot,
                                               float* __restrict__ S2) {
    __shared__ float ls[128][65];
    const int tid = threadIdx.x;
    const int cl = tid & 63;
    const int ch = tid >> 6;              // 0..3 (local chunk)
    const int col = blockIdx.x * 64 + cl;
    const int chg = blockIdx.y * 4 + ch;  // global chunk
    const int t0 = chg * SC_L;

    constexpr float gL = gpw(SC_L);

    float carry = 0.f, f = 1.f;
    for (int j = chg - 1; j >= 0; --j) {
        carry += f * tot[(size_t)j * D_DIM + col];
        f *= gL;
    }

    float r = carry, s1 = 0.f;
    #pragma unroll 4
    for (int k = 0; k < SC_L; ++k) {
        const int t = t0 + k;
        const float a = (t == 0) ? 0.f : m[(size_t)t * D_DIM + col];
        r = GAMMA_F * r + a;
        ls[ch * SC_L + k][cl] = r;
        if (t == 1) s1 = r;
    }
    if (blockIdx.y == 0 && ch == 0) ls[0][cl] = s1;   // S[0] = S[1]
    __syncthreads();

    const int c0 = blockIdx.x * 64;
    const int tB = blockIdx.y * 128;
    for (int e = tid; e < 128 * 64; e += 256) {
        const int rr = e >> 6;            // 0..127
        const int j  = e & 63;
        const int hi = rr >> 6, cl2 = rr & 63;
        S2[(size_t)((hi << 10) + c0 + cl2) * D_DIM + (tB >> 1) + j] =
            ls[2 * j + hi][cl2];
    }
}

// ---------------------------------------------------------------------------
extern "C" void kernel_launch(void* const* d_in, const int* in_sizes, int n_in,
                              void* d_out, int out_size, void* d_ws, size_t ws_size,
                              hipStream_t stream) {
    const float* x  = (const float*)d_in[0];   // [4,2048,1024]
    const float* Wq = (const float*)d_in[1];
    const float* Wk = (const float*)d_in[2];
    const float* Wv = (const float*)d_in[3];
    float* out = (float*)d_out;                // [4,2048,1024] fp32
    char* ws = (char*)d_ws;

    // ws layout (41 MB):
    ushort* xb  = (ushort*)(ws);                    // 16 MB  [B*T,D] bf16
    float*  m   = (float*)(ws + (16u << 20));       //  8 MB  [T,D] fp32
    ushort* yb  = (ushort*)(ws + (24u << 20));      //  4 MB  [T,D] bf16
    ushort* WTk = (ushort*)(ws + (28u << 20));      //  2 MB
    ushort* WTq = (ushort*)(ws + (30u << 20));      //  2 MB
    float*  S2  = (float*)(ws + (32u << 20));       //  8 MB  scrambled S fp32
    float*  tot = (float*)(ws + (40u << 20));       //  256 KB (dedicated)
    float*  wv_sum = m;                 // m row 0: overwritten after use

    dim3 gP(32, 32, 3);
    k_prep<<<gP, 256, 0, stream>>>(Wk, Wq, Wv, WTk, WTq, wv_sum);

    k_vsum_y<<<T_DIM, 256, 0, stream>>>(x, wv_sum, (ushort*)yb, (ushort*)xb);

    // m = y @ Wk (+ fused scan1 -> tot): tile 128x64, grid (16,16), 8 waves
    dim3 gm(T_DIM / 128, D_DIM / 64);
    k_gemm<2, 2, 0><<<gm, 512, 0, stream>>>(yb, WTk, m, nullptr, tot);

    // carries + scramble
    dim3 gs(D_DIM / 64, SC_NC / 4);
    k_scan2<<<gs, 256, 0, stream>>>(m, tot, S2);

    // out = S2 ⊙ (x @ Wq) : tile 128x128, grid (64,8), 8 waves
    dim3 gq((4 * T_DIM) / 128, D_DIM / 128);
    k_gemm<2, 4, 1><<<gq, 512, 0, stream>>>(xb, WTq, out, S2, nullptr);
}